// Round 1
// baseline (532.558 us; speedup 1.0000x reference)
//
#include <hip/hip_runtime.h>
#include <math.h>

#define TT 512
#define BB 64
#define HH 512
#define KK 16

// ---------------------------------------------------------------------------
// Kernel 1: em = relu(hidden @ W1 + b1) @ W2 + b2      (fp32, fused)
// hidden: (T*B, H) row-major; W1: (H,H); W2: (H,K); em: (T*B, K)
// grid 512 blocks x 256 threads; BM=64 rows/block; N chunks of 128; K tiles 32
// ---------------------------------------------------------------------------
__global__ __launch_bounds__(256, 2)
void em_kernel(const float* __restrict__ hidden, const float* __restrict__ W1,
               const float* __restrict__ b1, const float* __restrict__ W2,
               const float* __restrict__ b2, float* __restrict__ em,
               float* __restrict__ out) {
    // union buffer: phase1 As[64][36] (2304) + Bs[32][132] (4224) = 6528 floats
    //               phase2 Hs[64][132] = 8448 floats
    __shared__ float uni[8448];
    __shared__ float W2s[128 * 16];
    float* As = uni;             // [64][36]  (pad 36: 2-way LDS aliasing only)
    float* Bs = uni + 64 * 36;   // [32][132]
    float* Hs = uni;             // [64][132]

    const int tx   = threadIdx.x;
    const int row0 = blockIdx.x * 64;

    if (blockIdx.x == 0 && tx == 0) out[0] = 0.0f;  // scan kernel atomicAdds later

    // phase-1 micro-tile mapping: 16 row-groups x 16 col-groups
    const int rg = tx >> 4;   // 0..15 -> rows rg*4..rg*4+3
    const int cg = tx & 15;   // 0..15 -> cols cg*8..cg*8+7
    // phase-2 mapping: 64 rows x 4 k-groups
    const int p2row = tx >> 2;  // 0..63
    const int p2kg  = tx & 3;   // 0..3 -> k = p2kg*4..p2kg*4+3

    float em_acc[4] = {0.f, 0.f, 0.f, 0.f};

    for (int nc = 0; nc < 4; ++nc) {
        const int n0 = nc * 128;

        __syncthreads();  // (a) previous phase-2 readers done (W2s/Hs safe to overwrite)

        // load W2 chunk: rows n0..n0+127, all 16 cols  (512 float4, 2/thread)
        {
            const float4* src = (const float4*)(W2 + n0 * KK);
            float4* dst = (float4*)W2s;
            dst[tx]       = src[tx];
            dst[tx + 256] = src[tx + 256];
        }

        float acc[4][8];
#pragma unroll
        for (int i = 0; i < 4; ++i)
#pragma unroll
            for (int j = 0; j < 8; ++j) acc[i][j] = 0.f;

        for (int kt = 0; kt < 16; ++kt) {
            const int k0 = kt * 32;
            __syncthreads();  // (b) previous tile's compute readers done
            // load A tile 64x32 -> As[64][36]
            {
                const int r = tx >> 3;         // 0..31
                const int c = (tx & 7) * 4;    // 0..28
                float4 v0 = *(const float4*)(hidden + (row0 + r) * HH + k0 + c);
                float4 v1 = *(const float4*)(hidden + (row0 + r + 32) * HH + k0 + c);
                *(float4*)(As + r * 36 + c)        = v0;
                *(float4*)(As + (r + 32) * 36 + c) = v1;
            }
            // load W1 tile 32x128 -> Bs[32][132]
            {
                const int c     = (tx & 31) * 4;  // 0..124
                const int rbase = tx >> 5;        // 0..7
#pragma unroll
                for (int i = 0; i < 4; ++i) {
                    const int r = rbase + i * 8;
                    float4 v = *(const float4*)(W1 + (k0 + r) * HH + n0 + c);
                    *(float4*)(Bs + r * 132 + c) = v;
                }
            }
            __syncthreads();  // (c) tiles ready
#pragma unroll
            for (int kk = 0; kk < 32; ++kk) {
                float a[4];
#pragma unroll
                for (int i = 0; i < 4; ++i) a[i] = As[(rg * 4 + i) * 36 + kk];
                float4 b0 = *(float4*)(Bs + kk * 132 + cg * 8);
                float4 b1v = *(float4*)(Bs + kk * 132 + cg * 8 + 4);
                float b[8] = {b0.x, b0.y, b0.z, b0.w, b1v.x, b1v.y, b1v.z, b1v.w};
#pragma unroll
                for (int i = 0; i < 4; ++i)
#pragma unroll
                    for (int j = 0; j < 8; ++j) acc[i][j] = fmaf(a[i], b[j], acc[i][j]);
            }
        }
        __syncthreads();  // (d) compute readers done; As/Bs region reusable as Hs

        // epilogue phase-1: +b1, relu, stash h chunk in LDS
#pragma unroll
        for (int j = 0; j < 8; ++j) {
            const float bias = b1[n0 + cg * 8 + j];
#pragma unroll
            for (int i = 0; i < 4; ++i) {
                float v = acc[i][j] + bias;
                v = v > 0.f ? v : 0.f;
                Hs[(rg * 4 + i) * 132 + cg * 8 + j] = v;
            }
        }
        __syncthreads();  // (e) Hs ready

        // phase-2: em_acc[k] += sum_j h[row][j] * W2[n0+j][p2kg*4+k]
        for (int j = 0; j < 128; j += 4) {
            float4 h4 = *(float4*)(Hs + p2row * 132 + j);
            const float hv[4] = {h4.x, h4.y, h4.z, h4.w};
#pragma unroll
            for (int q = 0; q < 4; ++q) {
                float4 w = *(float4*)(W2s + (j + q) * KK + p2kg * 4);
                em_acc[0] = fmaf(hv[q], w.x, em_acc[0]);
                em_acc[1] = fmaf(hv[q], w.y, em_acc[1]);
                em_acc[2] = fmaf(hv[q], w.z, em_acc[2]);
                em_acc[3] = fmaf(hv[q], w.w, em_acc[3]);
            }
        }
    }

    // write em row (add b2)
    float4 ov;
    ov.x = em_acc[0] + b2[p2kg * 4 + 0];
    ov.y = em_acc[1] + b2[p2kg * 4 + 1];
    ov.z = em_acc[2] + b2[p2kg * 4 + 2];
    ov.w = em_acc[3] + b2[p2kg * 4 + 3];
    *(float4*)(em + (row0 + p2row) * KK + p2kg * 4) = ov;
}

// ---------------------------------------------------------------------------
// Kernel 2: CRF forward scan + gold path + reduction.
// 16 blocks x 64 threads; each wave handles 4 batches (16 lanes per batch).
// lane = bq*16 + j; lane j keeps alpha[j], full alpha replicated via __shfl.
// ---------------------------------------------------------------------------
__global__ void scan_kernel(const float* __restrict__ em,
                            const float* __restrict__ trans,
                            const int* __restrict__ lens,
                            const int* __restrict__ tags,
                            float* __restrict__ out) {
    __shared__ float tr_s[256];
    __shared__ float partial[4];

    const int lane = threadIdx.x;   // 0..63
    const int bq   = lane >> 4;     // 0..3
    const int j    = lane & 15;     // state index
    const int b    = blockIdx.x * 4 + bq;
    const int base = bq << 4;

#pragma unroll
    for (int i = 0; i < 4; ++i) tr_s[lane * 4 + i] = trans[lane * 4 + i];
    __syncthreads();

    float tr[16];
#pragma unroll
    for (int i = 0; i < 16; ++i) tr[i] = trans[j * 16 + i];

    const int L = lens[b];

    // t = 0
    float e   = em[b * KK + j];
    float cur = e;
    float a[16];
#pragma unroll
    for (int i = 0; i < 16; ++i) a[i] = __shfl(cur, base + i, 64);
    int   tag_prev = tags[b];
    float gold     = __shfl(e, base + tag_prev, 64);
    float saved    = (L == 1) ? cur : 0.0f;

    for (int t = 1; t < TT; ++t) {
        e = em[(t * BB + b) * KK + j];
        const int tag = tags[t * BB + b];

        float x[16];
        float m = -1e30f;
#pragma unroll
        for (int i = 0; i < 16; ++i) {
            x[i] = a[i] + tr[i];
            m = fmaxf(m, x[i]);
        }
        float s = 0.f;
#pragma unroll
        for (int i = 0; i < 16; ++i) s += __expf(x[i] - m);
        cur = e + m + __logf(s);

        if (t == L - 1) saved = cur;

        const float et   = __shfl(e, base + tag, 64);
        const float step = et + tr_s[tag * 16 + tag_prev];
        gold += (t < L) ? step : 0.0f;
        tag_prev = tag;

#pragma unroll
        for (int i = 0; i < 16; ++i) a[i] = __shfl(cur, base + i, 64);
    }

    // fwd = logsumexp over the 16 lanes of `saved` (xor<16 stays in-group)
    float m2 = saved;
#pragma unroll
    for (int d = 1; d < 16; d <<= 1) m2 = fmaxf(m2, __shfl_xor(m2, d, 64));
    float se = __expf(saved - m2);
#pragma unroll
    for (int d = 1; d < 16; d <<= 1) se += __shfl_xor(se, d, 64);
    const float fwd = m2 + __logf(se);

    if (j == 0) partial[bq] = fwd - gold;
    __syncthreads();
    if (lane == 0)
        atomicAdd(out, partial[0] + partial[1] + partial[2] + partial[3]);
}

extern "C" void kernel_launch(void* const* d_in, const int* in_sizes, int n_in,
                              void* d_out, int out_size, void* d_ws, size_t ws_size,
                              hipStream_t stream) {
    const float* hidden = (const float*)d_in[0];
    const float* W1     = (const float*)d_in[1];
    const float* b1     = (const float*)d_in[2];
    const float* W2     = (const float*)d_in[3];
    const float* b2     = (const float*)d_in[4];
    const float* trans  = (const float*)d_in[5];
    const int*   lens   = (const int*)d_in[6];
    const int*   tags   = (const int*)d_in[7];
    float* out = (float*)d_out;
    float* em  = (float*)d_ws;  // (T*B, K) fp32 = 2 MB

    em_kernel<<<512, 256, 0, stream>>>(hidden, W1, b1, W2, b2, em, out);
    scan_kernel<<<16, 64, 0, stream>>>(em, trans, lens, tags, out);
}

// Round 2
// 501.363 us; speedup vs baseline: 1.0622x; 1.0622x over previous
//
#include <hip/hip_runtime.h>
#include <hip/hip_bf16.h>

#define TT 512
#define BB 64
#define HH 512
#define KK 16

typedef __attribute__((ext_vector_type(8))) short bf16x8;
typedef __attribute__((ext_vector_type(4))) float f32x4;

__device__ __forceinline__ unsigned short f2bf(float f) {
    union { __hip_bfloat16 h; unsigned short u; } cvt;
    cvt.h = __float2bfloat16(f);
    return cvt.u;
}

// ---------------------------------------------------------------------------
// prep: W1 (512x512 f32, [k][n]) -> W1t (bf16 [n][k]); W2 (512x16) -> W2t (bf16 [n][k])
// blocks 0..63: 64x64 W1 tiles via LDS transpose; block 64: W2.
// ---------------------------------------------------------------------------
__global__ void prep_kernel(const float* __restrict__ W1, const float* __restrict__ W2,
                            unsigned short* __restrict__ W1t, unsigned short* __restrict__ W2t) {
    const int bi = blockIdx.x, tx = threadIdx.x;
    if (bi < 64) {
        __shared__ float Ls[64][65];
        const int ti = bi & 7, tj = bi >> 3;
        const int r0 = ti * 64, c0 = tj * 64;
        const int r = tx >> 4, c4 = (tx & 15) * 4;
#pragma unroll
        for (int i = 0; i < 4; ++i) {
            float4 v = *(const float4*)(W1 + (size_t)(r0 + r + 16 * i) * HH + c0 + c4);
            Ls[c4 + 0][r + 16 * i] = v.x;
            Ls[c4 + 1][r + 16 * i] = v.y;
            Ls[c4 + 2][r + 16 * i] = v.z;
            Ls[c4 + 3][r + 16 * i] = v.w;
        }
        __syncthreads();
        const int rn = tx >> 4, k4 = (tx & 15) * 4;
#pragma unroll
        for (int i = 0; i < 4; ++i) {
            const int n = rn + 16 * i;
            ushort4 o;
            o.x = f2bf(Ls[n][k4 + 0]);
            o.y = f2bf(Ls[n][k4 + 1]);
            o.z = f2bf(Ls[n][k4 + 2]);
            o.w = f2bf(Ls[n][k4 + 3]);
            *(ushort4*)(W1t + (size_t)(c0 + n) * HH + r0 + k4) = o;
        }
    } else {
        for (int idx = tx; idx < 16 * HH; idx += 256) {
            const int n = idx >> 9, k = idx & 511;
            W2t[idx] = f2bf(W2[k * KK + n]);
        }
    }
}

// ---------------------------------------------------------------------------
// em = relu(hidden @ W1 + b1) @ W2 + b2, bf16 MFMA both GEMMs, fp32 accum.
// 512 blocks x 256 thr. Block: 64 rows x 512 cols. Wave tile 32x256 (2x16 tiles).
// ---------------------------------------------------------------------------
__global__ __launch_bounds__(256, 2)
void em_kernel(const float* __restrict__ hidden, const unsigned short* __restrict__ W1t,
               const float* __restrict__ b1, const unsigned short* __restrict__ W2t,
               const float* __restrict__ b2, float* __restrict__ em, float* __restrict__ out) {
    __shared__ unsigned short W2ts[16 * 520];               // [16][520] bf16, row 1040 B
    __shared__ __align__(16) unsigned char stage[37888];    // As(5120) + Bs(32768) | Hb(33792)
    unsigned short* As = (unsigned short*)stage;            // [64][40] bf16 (row 80 B)
    unsigned short* Bs = (unsigned short*)(stage + 5120);   // [512][32] bf16 (row 64 B, k-swizzled)
    unsigned short* Hb = (unsigned short*)stage;            // [64][264] bf16 (row 528 B)

    const int tx = threadIdx.x;
    const int w = tx >> 6, lane = tx & 63;
    const int q = lane >> 4, nl = lane & 15;
    const int wm = w >> 1, wn = w & 1;
    const int row0 = blockIdx.x * 64;

    if (blockIdx.x == 0 && tx == 0) out[0] = 0.0f;

    // stage W2t fully into LDS (16 rows x 512 bf16; padded rows)
    for (int i = tx; i < 16 * 64; i += 256) {
        const int n = i >> 6, kc = i & 63;
        *(bf16x8*)(W2ts + n * 520 + kc * 8) = *(const bf16x8*)(W2t + n * HH + kc * 8);
    }

    f32x4 acc[2][16];
#pragma unroll
    for (int mt = 0; mt < 2; ++mt)
#pragma unroll
        for (int nt = 0; nt < 16; ++nt) acc[mt][nt] = (f32x4){0.f, 0.f, 0.f, 0.f};

    for (int kt = 0; kt < 16; ++kt) {
        const int k0 = kt * 32;
        __syncthreads();  // previous tile's readers done
        // --- stage A: hidden 64x32 fp32 -> bf16 As[64][40]
        {
            const int r = tx >> 2, c8 = (tx & 3) * 8;
            const float* src = hidden + (size_t)(row0 + r) * HH + k0 + c8;
            float4 v0 = *(const float4*)(src);
            float4 v1 = *(const float4*)(src + 4);
            bf16x8 o;
            o[0] = (short)f2bf(v0.x); o[1] = (short)f2bf(v0.y);
            o[2] = (short)f2bf(v0.z); o[3] = (short)f2bf(v0.w);
            o[4] = (short)f2bf(v1.x); o[5] = (short)f2bf(v1.y);
            o[6] = (short)f2bf(v1.z); o[7] = (short)f2bf(v1.w);
            *(bf16x8*)(As + r * 40 + c8) = o;
        }
        // --- stage B: W1t[0..512][k0..k0+32) -> Bs via global_load_lds (16B), src-swizzled
#pragma unroll
        for (int it = 0; it < 8; ++it) {
            const int c = it * 256 + tx;
            const int n = c >> 2, slot = c & 3;
            const int kc = slot ^ ((n >> 1) & 3);
            __builtin_amdgcn_global_load_lds(
                (const __attribute__((address_space(1))) void*)(W1t + (size_t)n * HH + k0 + kc * 8),
                (__attribute__((address_space(3))) void*)(Bs + c * 8),
                16, 0, 0);
        }
        __syncthreads();  // drains vmcnt (global_load_lds) + lgkm (ds_write)
        // --- compute: 2 A-frags, 16 B-frags, 32 MFMA
        bf16x8 af[2];
#pragma unroll
        for (int mt = 0; mt < 2; ++mt)
            af[mt] = *(const bf16x8*)(As + (32 * wm + 16 * mt + nl) * 40 + q * 8);
#pragma unroll
        for (int nt = 0; nt < 16; ++nt) {
            const int n = 256 * wn + 16 * nt + nl;
            const int slot = q ^ ((n >> 1) & 3);
            bf16x8 bf = *(const bf16x8*)(Bs + n * 32 + slot * 8);
            acc[0][nt] = __builtin_amdgcn_mfma_f32_16x16x32_bf16(af[0], bf, acc[0][nt], 0, 0, 0);
            acc[1][nt] = __builtin_amdgcn_mfma_f32_16x16x32_bf16(af[1], bf, acc[1][nt], 0, 0, 0);
        }
    }

    // --- epilogue: relu(acc+b1) -> Hb (bf16) per 256-col chunk, then GEMM2 via MFMA
    f32x4 acc2 = (f32x4){0.f, 0.f, 0.f, 0.f};
    for (int c = 0; c < 2; ++c) {
        __syncthreads();  // staging/compute or previous chunk's GEMM2 reads done
        if (wn == c) {
#pragma unroll
            for (int nt = 0; nt < 16; ++nt) {
                const float bv = b1[c * 256 + 16 * nt + nl];
#pragma unroll
                for (int mt = 0; mt < 2; ++mt) {
#pragma unroll
                    for (int r = 0; r < 4; ++r) {
                        float v = acc[mt][nt][r] + bv;
                        v = v > 0.f ? v : 0.f;
                        const int row = 32 * wm + 16 * mt + q * 4 + r;
                        Hb[row * 264 + nt * 16 + nl] = f2bf(v);
                    }
                }
            }
        }
        __syncthreads();  // Hb ready
        // GEMM2: wave w does rows 16w..16w+15, N=16, K=256 (8 MFMA k-steps)
#pragma unroll
        for (int ks = 0; ks < 8; ++ks) {
            bf16x8 a2 = *(const bf16x8*)(Hb + (16 * w + nl) * 264 + ks * 32 + q * 8);
            bf16x8 b2f = *(const bf16x8*)(W2ts + nl * 520 + c * 256 + ks * 32 + q * 8);
            acc2 = __builtin_amdgcn_mfma_f32_16x16x32_bf16(a2, b2f, acc2, 0, 0, 0);
        }
    }
    // write em rows (C-layout: col=nl, row=16w+q*4+r)
#pragma unroll
    for (int r = 0; r < 4; ++r) {
        const int row = row0 + 16 * w + q * 4 + r;
        em[(size_t)row * KK + nl] = acc2[r] + b2[nl];
    }
}

// ---------------------------------------------------------------------------
// CRF scan: 16 blocks x 64 thr (4 batches/wave, 16 lanes each). Deep prefetch,
// LDS double-buffered alpha broadcast, tree max/sum.
// ---------------------------------------------------------------------------
__global__ void scan_kernel(const float* __restrict__ em, const float* __restrict__ trans,
                            const int* __restrict__ lens, const int* __restrict__ tags,
                            float* __restrict__ out) {
    __shared__ float tr_s[256];
    __shared__ float al[2][64];
    __shared__ float el[2][64];
    __shared__ float partial[4];

    const int lane = threadIdx.x;
    const int bq = lane >> 4, j = lane & 15;
    const int b = blockIdx.x * 4 + bq;
    const int base = bq << 4;

#pragma unroll
    for (int i = 0; i < 4; ++i) tr_s[lane + 64 * i] = trans[lane + 64 * i];

    float tr[16];
#pragma unroll
    for (int i = 0; i < 16; ++i) tr[i] = trans[j * 16 + i];

    const int L = lens[b];

    float ebuf[8];
    int tgbuf[8];
#pragma unroll
    for (int i = 0; i < 8; ++i) {
        ebuf[i] = em[(size_t)(i * BB + b) * KK + j];
        tgbuf[i] = tags[i * BB + b];
    }

    // t = 0
    float cur = ebuf[0];
    int tag_prev = tgbuf[0];
    float saved = (L == 1) ? cur : 0.0f;
    al[0][lane] = cur;
    el[0][lane] = ebuf[0];
    __syncthreads();
    float gold = el[0][base + tag_prev];

    for (int t = 1; t < TT; ++t) {
        const int s = t & 7;
        const float e = ebuf[s];
        const int tag = tgbuf[s];
        const int tn = t + 8;
        if (tn < TT) {  // prefetch 8 ahead (uniform branch)
            ebuf[s] = em[(size_t)(tn * BB + b) * KK + j];
            tgbuf[s] = tags[tn * BB + b];
        }
        const int p = t & 1, pp = p ^ 1;
        float4 A0 = *(float4*)&al[pp][base];
        float4 A1 = *(float4*)&al[pp][base + 4];
        float4 A2 = *(float4*)&al[pp][base + 8];
        float4 A3 = *(float4*)&al[pp][base + 12];
        float x[16];
        x[0] = A0.x + tr[0];  x[1] = A0.y + tr[1];  x[2] = A0.z + tr[2];  x[3] = A0.w + tr[3];
        x[4] = A1.x + tr[4];  x[5] = A1.y + tr[5];  x[6] = A1.z + tr[6];  x[7] = A1.w + tr[7];
        x[8] = A2.x + tr[8];  x[9] = A2.y + tr[9];  x[10] = A2.z + tr[10]; x[11] = A2.w + tr[11];
        x[12] = A3.x + tr[12]; x[13] = A3.y + tr[13]; x[14] = A3.z + tr[14]; x[15] = A3.w + tr[15];
        // tree max
        float m8[8];
#pragma unroll
        for (int i = 0; i < 8; ++i) m8[i] = fmaxf(x[2 * i], x[2 * i + 1]);
        float m4a = fmaxf(m8[0], m8[1]), m4b = fmaxf(m8[2], m8[3]);
        float m4c = fmaxf(m8[4], m8[5]), m4d = fmaxf(m8[6], m8[7]);
        const float m = fmaxf(fmaxf(m4a, m4b), fmaxf(m4c, m4d));
        // tree sum of exps
        float ex[16];
#pragma unroll
        for (int i = 0; i < 16; ++i) ex[i] = __expf(x[i] - m);
        float s8[8];
#pragma unroll
        for (int i = 0; i < 8; ++i) s8[i] = ex[2 * i] + ex[2 * i + 1];
        float s4a = s8[0] + s8[1], s4b = s8[2] + s8[3];
        float s4c = s8[4] + s8[5], s4d = s8[6] + s8[7];
        const float ssum = (s4a + s4b) + (s4c + s4d);
        cur = e + m + __logf(ssum);
        if (t == L - 1) saved = cur;
        al[p][lane] = cur;
        el[p][lane] = e;
        __syncthreads();
        if (t < L) gold += el[p][base + tag] + tr_s[tag * 16 + tag_prev];
        tag_prev = tag;
    }

    // lse over 16 lanes of `saved`
    float m2 = saved;
#pragma unroll
    for (int d = 1; d < 16; d <<= 1) m2 = fmaxf(m2, __shfl_xor(m2, d, 64));
    float se = __expf(saved - m2);
#pragma unroll
    for (int d = 1; d < 16; d <<= 1) se += __shfl_xor(se, d, 64);
    const float fwd = m2 + __logf(se);

    if (j == 0) partial[bq] = fwd - gold;
    __syncthreads();
    if (lane == 0)
        atomicAdd(out, partial[0] + partial[1] + partial[2] + partial[3]);
}

extern "C" void kernel_launch(void* const* d_in, const int* in_sizes, int n_in,
                              void* d_out, int out_size, void* d_ws, size_t ws_size,
                              hipStream_t stream) {
    const float* hidden = (const float*)d_in[0];
    const float* W1     = (const float*)d_in[1];
    const float* b1     = (const float*)d_in[2];
    const float* W2     = (const float*)d_in[3];
    const float* b2     = (const float*)d_in[4];
    const float* trans  = (const float*)d_in[5];
    const int*   lens   = (const int*)d_in[6];
    const int*   tags   = (const int*)d_in[7];
    float* out = (float*)d_out;

    float* em = (float*)d_ws;                                        // 2 MB
    unsigned short* W1t = (unsigned short*)((char*)d_ws + (size_t)TT * BB * KK * 4);
    unsigned short* W2t = W1t + (size_t)HH * HH;                     // +16 KB

    prep_kernel<<<65, 256, 0, stream>>>(W1, W2, W1t, W2t);
    em_kernel<<<512, 256, 0, stream>>>(hidden, W1t, b1, W2t, b2, em, out);
    scan_kernel<<<16, 64, 0, stream>>>(em, trans, lens, tags, out);
}

// Round 3
// 260.614 us; speedup vs baseline: 2.0435x; 1.9238x over previous
//
#include <hip/hip_runtime.h>
#include <hip/hip_bf16.h>

#define TT 512
#define BB 64
#define HH 512
#define KK 16

typedef __attribute__((ext_vector_type(8))) short bf16x8;
typedef __attribute__((ext_vector_type(4))) float f32x4;

__device__ __forceinline__ unsigned short f2bf(float f) {
    union { __hip_bfloat16 h; unsigned short u; } cvt;
    cvt.h = __float2bfloat16(f);
    return cvt.u;
}

// ---------------------------------------------------------------------------
// prep: W1 (512x512 f32, [k][n]) -> W1t (bf16 [n][k]); W2 (512x16) -> W2t (bf16 [n][k])
// ---------------------------------------------------------------------------
__global__ void prep_kernel(const float* __restrict__ W1, const float* __restrict__ W2,
                            unsigned short* __restrict__ W1t, unsigned short* __restrict__ W2t) {
    const int bi = blockIdx.x, tx = threadIdx.x;
    if (bi < 64) {
        __shared__ float Ls[64][65];
        const int ti = bi & 7, tj = bi >> 3;
        const int r0 = ti * 64, c0 = tj * 64;
        const int r = tx >> 4, c4 = (tx & 15) * 4;
#pragma unroll
        for (int i = 0; i < 4; ++i) {
            float4 v = *(const float4*)(W1 + (size_t)(r0 + r + 16 * i) * HH + c0 + c4);
            Ls[c4 + 0][r + 16 * i] = v.x;
            Ls[c4 + 1][r + 16 * i] = v.y;
            Ls[c4 + 2][r + 16 * i] = v.z;
            Ls[c4 + 3][r + 16 * i] = v.w;
        }
        __syncthreads();
        const int rn = tx >> 4, k4 = (tx & 15) * 4;
#pragma unroll
        for (int i = 0; i < 4; ++i) {
            const int n = rn + 16 * i;
            ushort4 o;
            o.x = f2bf(Ls[n][k4 + 0]);
            o.y = f2bf(Ls[n][k4 + 1]);
            o.z = f2bf(Ls[n][k4 + 2]);
            o.w = f2bf(Ls[n][k4 + 3]);
            *(ushort4*)(W1t + (size_t)(c0 + n) * HH + r0 + k4) = o;
        }
    } else {
        for (int idx = tx; idx < 16 * HH; idx += 256) {
            const int n = idx >> 9, k = idx & 511;
            W2t[idx] = f2bf(W2[k * KK + n]);
        }
    }
}

// ---------------------------------------------------------------------------
// em = relu(hidden @ W1 + b1) @ W2 + b2, bf16 MFMA both GEMMs, fp32 accum.
// ---------------------------------------------------------------------------
__global__ __launch_bounds__(256, 2)
void em_kernel(const float* __restrict__ hidden, const unsigned short* __restrict__ W1t,
               const float* __restrict__ b1, const unsigned short* __restrict__ W2t,
               const float* __restrict__ b2, float* __restrict__ em, float* __restrict__ out) {
    __shared__ unsigned short W2ts[16 * 520];
    __shared__ __align__(16) unsigned char stage[37888];
    unsigned short* As = (unsigned short*)stage;            // [64][40] bf16
    unsigned short* Bs = (unsigned short*)(stage + 5120);   // [512][32] bf16, k-swizzled
    unsigned short* Hb = (unsigned short*)stage;            // [64][264] bf16

    const int tx = threadIdx.x;
    const int w = tx >> 6, lane = tx & 63;
    const int q = lane >> 4, nl = lane & 15;
    const int wm = w >> 1, wn = w & 1;
    const int row0 = blockIdx.x * 64;

    if (blockIdx.x == 0 && tx == 0) out[0] = 0.0f;

    for (int i = tx; i < 16 * 64; i += 256) {
        const int n = i >> 6, kc = i & 63;
        *(bf16x8*)(W2ts + n * 520 + kc * 8) = *(const bf16x8*)(W2t + n * HH + kc * 8);
    }

    f32x4 acc[2][16];
#pragma unroll
    for (int mt = 0; mt < 2; ++mt)
#pragma unroll
        for (int nt = 0; nt < 16; ++nt) acc[mt][nt] = (f32x4){0.f, 0.f, 0.f, 0.f};

    for (int kt = 0; kt < 16; ++kt) {
        const int k0 = kt * 32;
        __syncthreads();
        {
            const int r = tx >> 2, c8 = (tx & 3) * 8;
            const float* src = hidden + (size_t)(row0 + r) * HH + k0 + c8;
            float4 v0 = *(const float4*)(src);
            float4 v1 = *(const float4*)(src + 4);
            bf16x8 o;
            o[0] = (short)f2bf(v0.x); o[1] = (short)f2bf(v0.y);
            o[2] = (short)f2bf(v0.z); o[3] = (short)f2bf(v0.w);
            o[4] = (short)f2bf(v1.x); o[5] = (short)f2bf(v1.y);
            o[6] = (short)f2bf(v1.z); o[7] = (short)f2bf(v1.w);
            *(bf16x8*)(As + r * 40 + c8) = o;
        }
#pragma unroll
        for (int it = 0; it < 8; ++it) {
            const int c = it * 256 + tx;
            const int n = c >> 2, slot = c & 3;
            const int kc = slot ^ ((n >> 1) & 3);
            __builtin_amdgcn_global_load_lds(
                (const __attribute__((address_space(1))) void*)(W1t + (size_t)n * HH + k0 + kc * 8),
                (__attribute__((address_space(3))) void*)(Bs + c * 8),
                16, 0, 0);
        }
        __syncthreads();
        bf16x8 af[2];
#pragma unroll
        for (int mt = 0; mt < 2; ++mt)
            af[mt] = *(const bf16x8*)(As + (32 * wm + 16 * mt + nl) * 40 + q * 8);
#pragma unroll
        for (int nt = 0; nt < 16; ++nt) {
            const int n = 256 * wn + 16 * nt + nl;
            const int slot = q ^ ((n >> 1) & 3);
            bf16x8 bf = *(const bf16x8*)(Bs + n * 32 + slot * 8);
            acc[0][nt] = __builtin_amdgcn_mfma_f32_16x16x32_bf16(af[0], bf, acc[0][nt], 0, 0, 0);
            acc[1][nt] = __builtin_amdgcn_mfma_f32_16x16x32_bf16(af[1], bf, acc[1][nt], 0, 0, 0);
        }
    }

    f32x4 acc2 = (f32x4){0.f, 0.f, 0.f, 0.f};
    for (int c = 0; c < 2; ++c) {
        __syncthreads();
        if (wn == c) {
#pragma unroll
            for (int nt = 0; nt < 16; ++nt) {
                const float bv = b1[c * 256 + 16 * nt + nl];
#pragma unroll
                for (int mt = 0; mt < 2; ++mt) {
#pragma unroll
                    for (int r = 0; r < 4; ++r) {
                        float v = acc[mt][nt][r] + bv;
                        v = v > 0.f ? v : 0.f;
                        const int row = 32 * wm + 16 * mt + q * 4 + r;
                        Hb[row * 264 + nt * 16 + nl] = f2bf(v);
                    }
                }
            }
        }
        __syncthreads();
#pragma unroll
        for (int ks = 0; ks < 8; ++ks) {
            bf16x8 a2 = *(const bf16x8*)(Hb + (16 * w + nl) * 264 + ks * 32 + q * 8);
            bf16x8 b2f = *(const bf16x8*)(W2ts + nl * 520 + c * 256 + ks * 32 + q * 8);
            acc2 = __builtin_amdgcn_mfma_f32_16x16x32_bf16(a2, b2f, acc2, 0, 0, 0);
        }
    }
#pragma unroll
    for (int r = 0; r < 4; ++r) {
        const int row = row0 + 16 * w + q * 4 + r;
        em[(size_t)row * KK + nl] = acc2[r] + b2[nl];
    }
}

// ---------------------------------------------------------------------------
// CRF scan, exp-domain recurrence:  alpha_j = C + beta_j,  g_j = exp(beta_j)
//   S_i = sum_j g_j * exp(T[i][j]);  beta'_i = log(S_i) + e_i;  renorm every 4.
// One exp + one log per lane per step. 16 blocks x 64 thr, 4 batches/wave.
// Static-unrolled 8-deep prefetch (NO dynamic reg-array indexing -> no spill).
// ---------------------------------------------------------------------------
__global__ void scan_kernel(const float* __restrict__ em, const float* __restrict__ trans,
                            const int* __restrict__ lens, const int* __restrict__ tags,
                            float* __restrict__ out) {
    __shared__ float tr_s[256];
    __shared__ float partial[4];

    const int lane = threadIdx.x;
    const int bq = lane >> 4, j = lane & 15;
    const int b = blockIdx.x * 4 + bq;
    const int base = bq << 4;

#pragma unroll
    for (int i = 0; i < 4; ++i) tr_s[lane + 64 * i] = trans[lane + 64 * i];
    __syncthreads();

    // etr[i] = exp(T[own_state][i])
    float etr[16];
#pragma unroll
    for (int i = 0; i < 16; ++i) etr[i] = __expf(trans[j * 16 + i]);

    const int L = lens[b];

    float ebuf[8];
    int tgbuf[8];
#pragma unroll
    for (int i = 0; i < 8; ++i) {
        ebuf[i] = em[(size_t)(i * BB + b) * KK + j];
        tgbuf[i] = tags[i * BB + b];
    }

    // ---- t = 0 ----
    float beta = ebuf[0];          // C = 0
    float C = 0.0f;
    int tag_prev = tgbuf[0];
    float gold = __shfl(ebuf[0], base + tag_prev, 64);
    float bsv = beta, Csv = 0.0f;  // valid if L==1
    float g = __expf(beta);
    // refill slot 0 for t=8
    ebuf[0] = em[(size_t)(8 * BB + b) * KK + j];
    tgbuf[0] = tags[8 * BB + b];

#define DO_STEP(t_, s_, pf_, renorm_)                                          \
    {                                                                          \
        const float e = ebuf[s_];                                              \
        const int tag = tgbuf[s_];                                             \
        if (pf_) {                                                             \
            ebuf[s_] = em[(size_t)(((t_) + 8) * BB + b) * KK + j];             \
            tgbuf[s_] = tags[((t_) + 8) * BB + b];                             \
        }                                                                      \
        float gv[16];                                                          \
        _Pragma("unroll")                                                      \
        for (int i = 0; i < 16; ++i) gv[i] = __shfl(g, base + i, 64);          \
        float p8[8];                                                           \
        _Pragma("unroll")                                                      \
        for (int i = 0; i < 8; ++i)                                            \
            p8[i] = gv[2 * i] * etr[2 * i] + gv[2 * i + 1] * etr[2 * i + 1];   \
        const float s4a = p8[0] + p8[1], s4b = p8[2] + p8[3];                  \
        const float s4c = p8[4] + p8[5], s4d = p8[6] + p8[7];                  \
        const float S = (s4a + s4b) + (s4c + s4d);                             \
        float bt = __logf(S) + e;                                              \
        if (renorm_) {                                                         \
            const float Kx = __shfl(bt, base, 64);                             \
            bt -= Kx;                                                          \
            C += Kx;                                                           \
        }                                                                      \
        const float et = __shfl(e, base + tag, 64);                            \
        gold += ((t_) < L) ? (et + tr_s[tag * 16 + tag_prev]) : 0.0f;          \
        tag_prev = tag;                                                        \
        if ((t_) == L - 1) { bsv = bt; Csv = C; }                              \
        beta = bt;                                                             \
        g = __expf(bt);                                                        \
    }

    // ---- peeled t = 1..7 ----
#pragma unroll
    for (int s = 1; s < 8; ++s) {
        DO_STEP(s, s, true, ((s & 3) == 3));
    }
    // ---- main t = 8..511 ----
    for (int tb = 8; tb < TT; tb += 8) {
        const bool pf = (tb + 8 < TT);
#pragma unroll
        for (int s = 0; s < 8; ++s) {
            const int t = tb + s;
            DO_STEP(t, s, pf, ((s & 3) == 3));
        }
    }
#undef DO_STEP

    // fwd = Csv + lse over 16 lanes of bsv
    float m2 = bsv;
#pragma unroll
    for (int d = 1; d < 16; d <<= 1) m2 = fmaxf(m2, __shfl_xor(m2, d, 64));
    float se = __expf(bsv - m2);
#pragma unroll
    for (int d = 1; d < 16; d <<= 1) se += __shfl_xor(se, d, 64);
    const float fwd = Csv + m2 + __logf(se);

    if (j == 0) partial[bq] = fwd - gold;
    __syncthreads();
    if (lane == 0)
        atomicAdd(out, partial[0] + partial[1] + partial[2] + partial[3]);
}

extern "C" void kernel_launch(void* const* d_in, const int* in_sizes, int n_in,
                              void* d_out, int out_size, void* d_ws, size_t ws_size,
                              hipStream_t stream) {
    const float* hidden = (const float*)d_in[0];
    const float* W1     = (const float*)d_in[1];
    const float* b1     = (const float*)d_in[2];
    const float* W2     = (const float*)d_in[3];
    const float* b2     = (const float*)d_in[4];
    const float* trans  = (const float*)d_in[5];
    const int*   lens   = (const int*)d_in[6];
    const int*   tags   = (const int*)d_in[7];
    float* out = (float*)d_out;

    float* em = (float*)d_ws;
    unsigned short* W1t = (unsigned short*)((char*)d_ws + (size_t)TT * BB * KK * 4);
    unsigned short* W2t = W1t + (size_t)HH * HH;

    prep_kernel<<<65, 256, 0, stream>>>(W1, W2, W1t, W2t);
    em_kernel<<<512, 256, 0, stream>>>(hidden, W1t, b1, W2t, b2, em, out);
    scan_kernel<<<16, 64, 0, stream>>>(em, trans, lens, tags, out);
}